// Round 4
// baseline (233.671 us; speedup 1.0000x reference)
//
#include <hip/hip_runtime.h>

#define C_   256
#define HW_  1024
#define N_   16384
#define K_   8192
#define OUT_SZ   4194304
#define LOSS_OFF 4194304
#define IDX_OFF  4194305
#define MARGIN   0.3f    /* 8.1-sigma of 1-product pairwise score error (sigma~0.037) */

typedef __attribute__((ext_vector_type(8)))  short short8;
typedef __attribute__((ext_vector_type(4)))  float f32x4;

// ---- ws layout (bytes): Bh 4MB | cnorm | ncnorm | list | cnt | fidx (~4.39 MB, ws proven >=10.26 MB) ----
#define BH_OFF     0u
#define CNORM_OFF  4194304u
#define NCNORM_OFF 4227072u
#define LIST_OFF   4259840u
#define CNT_OFF    4325376u
#define FIDX_OFF   4325440u
#define WS_NEED    4390976u

// ---- fallback ws layout (round-1 proven) ----
#define FB_CNORM   0u
#define FB_BESTS   32768u
#define FB_BESTK   557056u
#define FB_FIDX    1081344u

__device__ __forceinline__ unsigned short f2bf_rne(float x) {
  unsigned u = __float_as_uint(x);
  unsigned r = (u + 0x7fffu + ((u >> 16) & 1u)) >> 16;
  return (unsigned short)r;
}
__device__ __forceinline__ float bf2f(unsigned short h) {
  return __uint_as_float(((unsigned)h) << 16);
}
__device__ __forceinline__ void gld16(const void* g, void* l) {
  __builtin_amdgcn_global_load_lds((const __attribute__((address_space(1))) unsigned*)g,
                                   (__attribute__((address_space(3))) unsigned*)l, 16, 0, 0);
}
__device__ __forceinline__ float med3(float a, float b, float c) {
#if __has_builtin(__builtin_amdgcn_fmed3f)
  return __builtin_amdgcn_fmed3f(a, b, c);
#else
  return fmaxf(fminf(fmaxf(a, b), c), fminf(a, b));
#endif
}

// fused: blocks [0,2048): emb -> bf16-hi + (+/-)0.5||e||^2; blocks [2048,3072): inp -> bf16-hi A
__global__ __launch_bounds__(256) void conv_fused(const float* __restrict__ inp,
                                                  const float* __restrict__ emb,
                                                  unsigned short* __restrict__ Ah,
                                                  unsigned short* __restrict__ Bh,
                                                  float* __restrict__ cnorm,
                                                  float* __restrict__ ncnorm,
                                                  float* __restrict__ loss_slot,
                                                  int* __restrict__ counter) {
  __shared__ float T[64][65];
  int tid = threadIdx.x;
  if (blockIdx.x < 2048) {
    int wave = tid >> 6, lane = tid & 63;
    int k = blockIdx.x * 4 + wave;
    float4 v = *(const float4*)(emb + (size_t)k * C_ + lane * 4);
    float ss = v.x*v.x + v.y*v.y + v.z*v.z + v.w*v.w;
    #pragma unroll
    for (int m = 32; m > 0; m >>= 1) ss += __shfl_xor(ss, m);
    if (lane == 0) { cnorm[k] = 0.5f * ss; ncnorm[k] = -0.5f * ss; }
    uint2 p;
    p.x = (unsigned)f2bf_rne(v.x) | ((unsigned)f2bf_rne(v.y) << 16);
    p.y = (unsigned)f2bf_rne(v.z) | ((unsigned)f2bf_rne(v.w) << 16);
    *(uint2*)&Bh[(size_t)k * C_ + lane * 4] = p;
    if (blockIdx.x == 0 && tid == 0) { *loss_slot = 0.0f; *counter = 0; }
  } else {
    int bb = blockIdx.x - 2048;
    int nt = bb >> 2, ct = bb & 3;
    int n0 = nt * 64, c0 = ct * 64;
    int b = n0 >> 10, hw0 = n0 & 1023;
    const float* base = inp + (size_t)b * (C_ * HW_) + hw0;
    #pragma unroll
    for (int i = 0; i < 16; ++i) {
      int cl = i * 4 + (tid >> 6), nl = tid & 63;
      T[nl][cl] = base[(size_t)(c0 + cl) * HW_ + nl];
    }
    __syncthreads();
    #pragma unroll
    for (int i = 0; i < 16; ++i) {
      int nl = i * 4 + (tid >> 6), cl = tid & 63;
      Ah[(size_t)(n0 + nl) * C_ + c0 + cl] = f2bf_rne(T[nl][cl]);
    }
  }
}

// 1-product hh MFMA GEMM; per-(row, 256-sub) top-3 records -> d_out[8MB,16MB), nbe-major.
// Block 128 rows x 1024 codes (4 subs); 4 waves 2x2; swapped operands (codes=M, rows=N).
// v5: chunk-major LDS [kchunk][row][16B] -> conflict-free ds_read_b128 (old XOR swizzle
//     only used qm&3 -> exact 4-way conflict, 6.29M cycles/dispatch).
//     acc init = -0.5||e||^2 (ncnorm) -> epilogue drops the per-elem subtract.
//     med3 top-3 insert: 3 ops/elem (max + 2 med3), 6-op triple merge.
__global__ __launch_bounds__(256, 2) void k_gemm1p(const unsigned short* __restrict__ Ah,
                                                   const unsigned short* __restrict__ Bh,
                                                   const float* __restrict__ ncnorm,
                                                   uint4* __restrict__ Rec) {
  // per buffer (shorts): A [0,4096) = 4 chunks x 128 rows x 8; B [4096,12288) = 4 x 256 x 8
  __shared__ __align__(16) unsigned short LDS[2][12288];
  __shared__ float mS[2][128][3];

  const int tid = threadIdx.x, lane = tid & 63, wave = tid >> 6;
  const int wr = wave >> 1, wc = wave & 1;
  const int rb = blockIdx.x >> 3, kb = blockIdx.x & 7;
  const int row0 = rb * 128;
  const int qm = lane & 15, quad = lane >> 4;

  // staging: thread g stages 16B chunk; dest g*16 linear == [ch][row] layout
  const char* srcA[2]; int dstA[2];
  #pragma unroll
  for (int t = 0; t < 2; ++t) {
    int g = t * 256 + tid;                       // ch = g>>7, row = g&127
    srcA[t] = (const char*)Ah + (size_t)(row0 + (g & 127)) * 512 + ((g >> 7) & 3) * 16;
    dstA[t] = g * 16;
  }
  const char* srcB[4]; int dstB[4];
  #pragma unroll
  for (int t = 0; t < 4; ++t) {
    int g = t * 256 + tid;                       // ch = g>>8, r = g&255
    srcB[t] = (const char*)Bh + (size_t)(kb * 1024 + (g & 255)) * 512 + (g >> 8) * 16;
    dstB[t] = 8192 + g * 16;
  }

  // prologue: stage (sub=0, ci=0) into buffer 0
  #pragma unroll
  for (int t = 0; t < 2; ++t) gld16(srcA[t], (char*)LDS[0] + dstA[t]);
  #pragma unroll
  for (int t = 0; t < 4; ++t) gld16(srcB[t], (char*)LDS[0] + dstB[t]);
  __syncthreads();

  const int aBase = quad * 1024 + wr * 512 + qm * 8;           // shorts
  const int bBase = 4096 + quad * 2048 + wc * 1024 + qm * 8;   // shorts
  const unsigned wq  = (unsigned)(wc * 128 + quad * 4);        // embed bits 7, 3:2
  const unsigned kmk = 0xFFFFFF00u;

  for (int sub = 0; sub < 4; ++sub) {
    const int nbe = kb * 4 + sub;
    // acc init = -cnorm (code = wc*128 + ct*16 + quad*4 + rg; same for all rt)
    const int cb = nbe * 256 + wc * 128 + quad * 4;
    f32x4 acc[4][8];
    {
      float4 ncn[8];
      #pragma unroll
      for (int ct = 0; ct < 8; ++ct) ncn[ct] = *(const float4*)(ncnorm + cb + ct * 16);
      #pragma unroll
      for (int r = 0; r < 4; ++r)
        #pragma unroll
        for (int c = 0; c < 8; ++c) {
          acc[r][c][0] = ncn[c].x; acc[r][c][1] = ncn[c].y;
          acc[r][c][2] = ncn[c].z; acc[r][c][3] = ncn[c].w;
        }
    }

    #pragma unroll 2
    for (int ci = 0; ci < 8; ++ci) {
      const int it = (sub << 3) | ci;
      const int cur = ci & 1;                          // == it&1 (sub*8 even)
      const int nx = it + 1;
      if (nx < 32) {                                   // issue next tile FIRST (overlap)
        const int nsub = nx >> 3, nci = nx & 7, nb = nx & 1;
        #pragma unroll
        for (int t = 0; t < 2; ++t)
          gld16(srcA[t] + nci * 64, (char*)LDS[nb] + dstA[t]);
        #pragma unroll
        for (int t = 0; t < 4; ++t)
          gld16(srcB[t] + nsub * 131072 + nci * 64, (char*)LDS[nb] + dstB[t]);
      }

      const unsigned short* Lb = &LDS[cur][0];
      short8 ah[4];
      #pragma unroll
      for (int rt = 0; rt < 4; ++rt)
        ah[rt] = *(const short8*)&Lb[aBase + rt * 128];
      #pragma unroll
      for (int ch2 = 0; ch2 < 2; ++ch2) {
        short8 bh[4];
        #pragma unroll
        for (int q = 0; q < 4; ++q)
          bh[q] = *(const short8*)&Lb[bBase + (ch2 * 4 + q) * 128];
        #pragma unroll
        for (int rt = 0; rt < 4; ++rt)
          #pragma unroll
          for (int q = 0; q < 4; ++q)                  // SWAPPED: codes=A(M), rows=B(N)
            acc[rt][ch2 * 4 + q] =
              __builtin_amdgcn_mfma_f32_16x16x32_bf16(bh[q], ah[rt], acc[rt][ch2 * 4 + q], 0, 0, 0);
      }
      __syncthreads();                                 // drains this iter's stage; 1 barrier/iter
    }

    // epilogue: lane owns row (wr*64+rt*16+qm); acc already = score (cn folded into init).
    // key = score with low 8 mantissa bits = local k; med3 insert (3 ops/elem).
    #pragma unroll
    for (int rt = 0; rt < 4; ++rt) {
      float t1 = -3.4e38f, t2 = t1, t3 = t1;
      #pragma unroll
      for (int ct = 0; ct < 8; ++ct)
        #pragma unroll
        for (int rg = 0; rg < 4; ++rg) {
          unsigned idxv = wq | (unsigned)(ct * 16 + rg);
          float kf = __uint_as_float((__float_as_uint(acc[rt][ct][rg]) & kmk) | idxv);
          float n3 = med3(t2, kf, t3);
          float n2 = med3(t1, kf, t2);
          t1 = fmaxf(t1, kf);
          t2 = n2; t3 = n3;
        }
      #pragma unroll
      for (int m = 16; m < 64; m <<= 1) {              // merge 4 quads (2 steps, 6 ops each)
        float b1 = __shfl_xor(t1, m), b2 = __shfl_xor(t2, m), b3 = __shfl_xor(t3, m);
        float n3 = med3(t2, b1, t3);
        float n2 = med3(t1, b1, t2);
        t1 = fmaxf(t1, b1); t2 = n2; t3 = n3;
        n3 = med3(t2, b2, t3); t2 = fmaxf(t2, b2); t3 = n3;
        t3 = fmaxf(t3, b3);
      }
      if (quad == 0) {
        int rowl = wr * 64 + rt * 16 + qm;
        mS[wc][rowl][0] = t1; mS[wc][rowl][1] = t2; mS[wc][rowl][2] = t3;
      }
    }
    __syncthreads();
    if (tid < 128) {
      float s1 = mS[0][tid][0], s2 = mS[0][tid][1], s3 = mS[0][tid][2];
      float b1 = mS[1][tid][0], b2 = mS[1][tid][1], b3 = mS[1][tid][2];
      float n3 = med3(s2, b1, s3);
      float n2 = med3(s1, b1, s2);
      s1 = fmaxf(s1, b1); s2 = n2; s3 = n3;
      n3 = med3(s2, b2, s3); s2 = fmaxf(s2, b2); s3 = n3;
      s3 = fmaxf(s3, b3);
      unsigned u1 = __float_as_uint(s1), u2 = __float_as_uint(s2), u3 = __float_as_uint(s3);
      uint4 rec;
      rec.x = u1 & kmk;                                // clobbered score (err <= 0.008)
      rec.y = ((unsigned)f2bf_rne(__uint_as_float(u2 & kmk)) << 16)
            |  (unsigned)f2bf_rne(__uint_as_float(u3 & kmk));
      rec.z = (u1 & 255u) | ((u2 & 255u) << 8) | ((u3 & 255u) << 16);
      rec.w = 0u;
      Rec[(size_t)nbe * N_ + row0 + tid] = rec;        // nbe-major: coalesced store
    }
    // no trailing barrier needed: next mS write is >=8 iteration barriers away
  }
}

// per row: global hh-max over 32 subs; count candidates within MARGIN; decide or flag
__global__ __launch_bounds__(64) void k_merge3(const uint4* __restrict__ Rec,
                                               int* __restrict__ fidx,
                                               float* __restrict__ outIdx,
                                               int* __restrict__ list,
                                               int* __restrict__ counter) {
  int row = blockIdx.x * 64 + threadIdx.x;
  float g1 = -3.4e38f; int gk = 0;
  #pragma unroll
  for (int s = 0; s < 32; ++s) {
    uint4 v = Rec[(size_t)s * N_ + row];               // coalesced (nbe-major)
    float s1 = __uint_as_float(v.x);
    if (s1 > g1) { g1 = s1; gk = s * 256 + (int)(v.z & 255u); }
  }
  float thr = g1 - MARGIN;
  int cnt = 0;
  #pragma unroll
  for (int s = 0; s < 32; ++s) {
    uint4 v = Rec[(size_t)s * N_ + row];
    cnt += (__uint_as_float(v.x) >= thr);
    cnt += (bf2f((unsigned short)(v.y >> 16)) >= thr);
    cnt += (bf2f((unsigned short)(v.y & 0xffffu)) >= thr);
  }
  if (cnt == 1) { fidx[row] = gk; outIdx[row] = (float)gk; }
  else { int p = atomicAdd(counter, 1); list[p] = row; }
}

// exact fp32 refine for flagged rows: candidates (<=96) from records, wave-per-candidate dots
__global__ __launch_bounds__(256) void k_refine(const float* __restrict__ inp,
                                                const float* __restrict__ emb,
                                                const float* __restrict__ cnorm,
                                                const uint4* __restrict__ Rec,
                                                const int* __restrict__ list,
                                                const int* __restrict__ counter,
                                                int* __restrict__ fidx,
                                                float* __restrict__ outIdx) {
  __shared__ float f[256];
  __shared__ float ls1[32];
  __shared__ int   ck[96];
  __shared__ float csc[96];
  __shared__ int   ncand;
  int tid = threadIdx.x, lane = tid & 63, wv = tid >> 6;
  int count = *counter;
  for (int i = blockIdx.x; i < count; i += 4096) {
    int row = list[i];
    __syncthreads();
    f[tid] = inp[(size_t)(row >> 10) * (C_ * HW_) + (size_t)tid * HW_ + (row & 1023)];
    if (tid == 0) ncand = 0;
    if (tid < 32) ls1[tid] = __uint_as_float(Rec[(size_t)tid * N_ + row].x);
    __syncthreads();
    float g1 = ls1[0];
    #pragma unroll
    for (int s = 1; s < 32; ++s) g1 = fmaxf(g1, ls1[s]);
    float thr = g1 - MARGIN;
    if (tid < 32) {
      uint4 v = Rec[(size_t)tid * N_ + row];
      float s1 = __uint_as_float(v.x);
      float s2 = bf2f((unsigned short)(v.y >> 16));
      float s3 = bf2f((unsigned short)(v.y & 0xffffu));
      int b = tid * 256;
      if (s1 >= thr) { int p = atomicAdd(&ncand, 1); ck[p] = b + (int)(v.z & 255u); }
      if (s2 >= thr) { int p = atomicAdd(&ncand, 1); ck[p] = b + (int)((v.z >> 8) & 255u); }
      if (s3 >= thr) { int p = atomicAdd(&ncand, 1); ck[p] = b + (int)((v.z >> 16) & 255u); }
    }
    __syncthreads();
    int nc = ncand;
    for (int c = wv; c < nc; c += 4) {
      int k = ck[c];
      float4 e = ((const float4*)(emb + (size_t)k * C_))[lane];
      float d = f[lane*4]*e.x + f[lane*4+1]*e.y + f[lane*4+2]*e.z + f[lane*4+3]*e.w;
      #pragma unroll
      for (int m = 32; m > 0; m >>= 1) d += __shfl_xor(d, m);
      if (lane == 0) csc[c] = d - cnorm[k];
    }
    __syncthreads();
    if (tid == 0) {
      float bs = csc[0]; int bk = ck[0];
      for (int c = 1; c < nc; ++c)
        if (csc[c] > bs || (csc[c] == bs && ck[c] < bk)) { bs = csc[c]; bk = ck[c]; }
      fidx[row] = bk; outIdx[row] = (float)bk;
    }
    __syncthreads();
  }
}

// gather emb[idx] -> NCHW output (overwrites the scratch in d_out) + commitment loss
__global__ __launch_bounds__(256) void k_out(const float* __restrict__ inp,
                                             const float* __restrict__ emb,
                                             const int* __restrict__ fidx,
                                             float* __restrict__ out,
                                             float* __restrict__ loss) {
  __shared__ float Q[32][260];
  int tid = threadIdx.x;
  int n0 = blockIdx.x * 32, b = n0 >> 10, hw0 = n0 & 1023;
  #pragma unroll
  for (int p = 0; p < 8; ++p) {
    int r = p * 4 + (tid >> 6);
    int kq = fidx[n0 + r];
    float4 v = *(const float4*)(emb + (size_t)kq * C_ + (tid & 63) * 4);
    *(float4*)&Q[r][(tid & 63) * 4] = v;
  }
  __syncthreads();
  int hwl = tid & 31, cl = tid >> 5;
  float lsum = 0.0f;
  #pragma unroll
  for (int p = 0; p < 32; ++p) {
    int c = p * 8 + cl;
    size_t a = (size_t)b * (C_ * HW_) + (size_t)c * HW_ + hw0 + hwl;
    float q = Q[hwl][c];
    float x = inp[a];
    out[a] = q;
    float dd = q - x; lsum += dd * dd;
  }
  #pragma unroll
  for (int m = 32; m > 0; m >>= 1) lsum += __shfl_xor(lsum, m);
  __shared__ float red[4];
  if ((tid & 63) == 0) red[tid >> 6] = lsum;
  __syncthreads();
  if (tid == 0)
    atomicAdd(loss, (red[0] + red[1] + red[2] + red[3]) * (0.25f / (float)OUT_SZ));
}

// ---------------- fallback path (round-1 fp32, proven) ----------------
__global__ __launch_bounds__(256) void k_norms_fb(const float* __restrict__ emb,
                                                  float* __restrict__ cnorm,
                                                  float* __restrict__ loss_slot) {
  int tid = threadIdx.x, wave = tid >> 6, lane = tid & 63;
  int k = blockIdx.x * 4 + wave;
  float4 v = *(const float4*)(emb + k * C_ + lane * 4);
  float s = v.x*v.x + v.y*v.y + v.z*v.z + v.w*v.w;
  #pragma unroll
  for (int m = 32; m > 0; m >>= 1) s += __shfl_xor(s, m);
  if (lane == 0) cnorm[k] = 0.5f * s;
  if (blockIdx.x == 0 && tid == 0) *loss_slot = 0.0f;
}

__global__ __launch_bounds__(256) void k_score_fb(const float* __restrict__ inp,
                                                  const float* __restrict__ emb,
                                                  const float* __restrict__ cnorm,
                                                  float* __restrict__ bestS,
                                                  int*   __restrict__ bestK) {
  __shared__ float As[16][132];
  __shared__ float Bs[16][132];
  const int tid = threadIdx.x;
  const int tx = tid & 15, ty = tid >> 4;
  const int rt = blockIdx.x >> 3, ks = blockIdx.x & 7;
  const int row0 = rt * 128;
  const float* Abase = inp + (row0 >> 10) * (C_ * HW_) + (row0 & 1023);
  const int kbase = ks * 1024;
  const int m4  = (tid & 31) << 2;
  const int ccA = tid >> 5;
  const int cc4 = (tid & 3) << 2;
  const int kkB = tid >> 2;

  float rS[8]; int rK[8];
  #pragma unroll
  for (int r = 0; r < 8; ++r) { rS[r] = -3.4e38f; rK[r] = 0; }

  for (int kt = 0; kt < 8; ++kt) {
    const int k0 = kbase + kt * 128;
    float acc[8][8];
    #pragma unroll
    for (int r = 0; r < 8; ++r)
      #pragma unroll
      for (int c = 0; c < 8; ++c) acc[r][c] = 0.f;

    for (int ci = 0; ci < 16; ++ci) {
      const int c0 = ci * 16;
      __syncthreads();
      #pragma unroll
      for (int p = 0; p < 2; ++p) {
        int cc = ccA + p * 8;
        float4 v = *(const float4*)(Abase + (c0 + cc) * HW_ + m4);
        *(float4*)(&As[cc][m4]) = v;
      }
      #pragma unroll
      for (int p = 0; p < 2; ++p) {
        int k = kkB + p * 64;
        float4 v = *(const float4*)(emb + (size_t)(k0 + k) * C_ + c0 + cc4);
        Bs[cc4 + 0][k] = v.x; Bs[cc4 + 1][k] = v.y;
        Bs[cc4 + 2][k] = v.z; Bs[cc4 + 3][k] = v.w;
      }
      __syncthreads();
      #pragma unroll
      for (int cc = 0; cc < 16; ++cc) {
        float4 a0 = *(const float4*)(&As[cc][ty * 8]);
        float4 a1 = *(const float4*)(&As[cc][ty * 8 + 4]);
        float4 b0 = *(const float4*)(&Bs[cc][tx * 8]);
        float4 b1 = *(const float4*)(&Bs[cc][tx * 8 + 4]);
        float a[8] = {a0.x, a0.y, a0.z, a0.w, a1.x, a1.y, a1.z, a1.w};
        float b[8] = {b0.x, b0.y, b0.z, b0.w, b1.x, b1.y, b1.z, b1.w};
        #pragma unroll
        for (int r = 0; r < 8; ++r)
          #pragma unroll
          for (int c = 0; c < 8; ++c) acc[r][c] += a[r] * b[c];
      }
    }
    float cn[8];
    {
      float4 c0v = *(const float4*)(cnorm + k0 + tx * 8);
      float4 c1v = *(const float4*)(cnorm + k0 + tx * 8 + 4);
      cn[0] = c0v.x; cn[1] = c0v.y; cn[2] = c0v.z; cn[3] = c0v.w;
      cn[4] = c1v.x; cn[5] = c1v.y; cn[6] = c1v.z; cn[7] = c1v.w;
    }
    #pragma unroll
    for (int r = 0; r < 8; ++r)
      #pragma unroll
      for (int c = 0; c < 8; ++c) {
        float s = acc[r][c] - cn[c];
        if (s > rS[r]) { rS[r] = s; rK[r] = k0 + tx * 8 + c; }
      }
  }
  #pragma unroll
  for (int r = 0; r < 8; ++r) {
    float s = rS[r]; int kk = rK[r];
    #pragma unroll
    for (int m = 1; m < 16; m <<= 1) {
      float so = __shfl_xor(s, m);
      int   ko = __shfl_xor(kk, m);
      if (so > s || (so == s && ko < kk)) { s = so; kk = ko; }
    }
    if (tx == 0) {
      int row = row0 + ty * 8 + r;
      bestS[ks * N_ + row] = s;
      bestK[ks * N_ + row] = kk;
    }
  }
}

__global__ __launch_bounds__(256) void k_merge_fb(const float* __restrict__ bestS,
                                                  const int*   __restrict__ bestK,
                                                  float* __restrict__ out_idx,
                                                  int*   __restrict__ fidx) {
  int n = blockIdx.x * 256 + threadIdx.x;
  float bs = -3.4e38f; int bk = 0x7fffffff;
  #pragma unroll
  for (int s = 0; s < 8; ++s) {
    float v = bestS[s * N_ + n];
    int  kk = bestK[s * N_ + n];
    if (v > bs || (v == bs && kk < bk)) { bs = v; bk = kk; }
  }
  out_idx[n] = (float)bk;
  fidx[n] = bk;
}

extern "C" void kernel_launch(void* const* d_in, const int* in_sizes, int n_in,
                              void* d_out, int out_size, void* d_ws, size_t ws_size,
                              hipStream_t stream) {
  const float* inp = (const float*)d_in[0];
  const float* emb = (const float*)d_in[1];
  float* out = (float*)d_out;
  char* ws = (char*)d_ws;

  if (ws_size >= (size_t)WS_NEED) {
    unsigned short* Ah = (unsigned short*)d_out;             // [0, 8MB) of d_out
    uint4* Rec = (uint4*)((char*)d_out + 8388608u);          // [8MB, 16MB) of d_out
    unsigned short* Bh = (unsigned short*)(ws + BH_OFF);
    float* cnorm   = (float*)(ws + CNORM_OFF);
    float* ncnorm  = (float*)(ws + NCNORM_OFF);
    int*   list    = (int*)(ws + LIST_OFF);
    int*   counter = (int*)(ws + CNT_OFF);
    int*   fidx    = (int*)(ws + FIDX_OFF);

    conv_fused <<<3072,   256, 0, stream>>>(inp, emb, Ah, Bh, cnorm, ncnorm,
                                            out + LOSS_OFF, counter);
    k_gemm1p   <<<1024,   256, 0, stream>>>(Ah, Bh, ncnorm, Rec);
    k_merge3   <<<N_/64,  64,  0, stream>>>(Rec, fidx, out + IDX_OFF, list, counter);
    k_refine   <<<4096,   256, 0, stream>>>(inp, emb, cnorm, Rec, list, counter,
                                            fidx, out + IDX_OFF);
    k_out      <<<N_/32,  256, 0, stream>>>(inp, emb, fidx, out, out + LOSS_OFF);
  } else {
    float* cnorm = (float*)(ws + FB_CNORM);
    float* bestS = (float*)(ws + FB_BESTS);
    int*   bestK = (int*)(ws + FB_BESTK);
    int*   fidx  = (int*)(ws + FB_FIDX);

    k_norms_fb <<<K_ / 4, 256, 0, stream>>>(emb, cnorm, out + LOSS_OFF);
    k_score_fb <<<1024,   256, 0, stream>>>(inp, emb, cnorm, bestS, bestK);
    k_merge_fb <<<N_/256, 256, 0, stream>>>(bestS, bestK, out + IDX_OFF, fidx);
    k_out      <<<OUT_SZ/8192, 256, 0, stream>>>(inp, emb, fidx, out, out + LOSS_OFF);
  }
}

// Round 5
// 188.941 us; speedup vs baseline: 1.2367x; 1.2367x over previous
//
#include <hip/hip_runtime.h>

#define C_   256
#define HW_  1024
#define N_   16384
#define K_   8192
#define OUT_SZ   4194304
#define LOSS_OFF 4194304
#define IDX_OFF  4194305
#define MARGIN   0.3f    /* 8.1-sigma of 1-product pairwise score error (sigma~0.037) */

typedef __attribute__((ext_vector_type(8)))  short short8;
typedef __attribute__((ext_vector_type(4)))  float f32x4;

// ---- ws layout (bytes): Bh 4MB | cnorm | ncnorm | list | cnt | fidx (~4.39 MB, ws proven >=10.26 MB) ----
#define BH_OFF     0u
#define CNORM_OFF  4194304u
#define NCNORM_OFF 4227072u
#define LIST_OFF   4259840u
#define CNT_OFF    4325376u
#define FIDX_OFF   4325440u
#define WS_NEED    4390976u

// ---- fallback ws layout (round-1 proven) ----
#define FB_CNORM   0u
#define FB_BESTS   32768u
#define FB_BESTK   557056u
#define FB_FIDX    1081344u

__device__ __forceinline__ unsigned short f2bf_rne(float x) {
  unsigned u = __float_as_uint(x);
  unsigned r = (u + 0x7fffu + ((u >> 16) & 1u)) >> 16;
  return (unsigned short)r;
}
__device__ __forceinline__ float bf2f(unsigned short h) {
  return __uint_as_float(((unsigned)h) << 16);
}
__device__ __forceinline__ void gld16(const void* g, void* l) {
  __builtin_amdgcn_global_load_lds((const __attribute__((address_space(1))) unsigned*)g,
                                   (__attribute__((address_space(3))) unsigned*)l, 16, 0, 0);
}
__device__ __forceinline__ float med3(float a, float b, float c) {
#if __has_builtin(__builtin_amdgcn_fmed3f)
  return __builtin_amdgcn_fmed3f(a, b, c);
#else
  return fmaxf(fminf(fmaxf(a, b), c), fminf(a, b));
#endif
}

// fused: blocks [0,2048): emb -> bf16-hi + (+/-)0.5||e||^2; blocks [2048,3072): inp -> bf16-hi A
__global__ __launch_bounds__(256) void conv_fused(const float* __restrict__ inp,
                                                  const float* __restrict__ emb,
                                                  unsigned short* __restrict__ Ah,
                                                  unsigned short* __restrict__ Bh,
                                                  float* __restrict__ cnorm,
                                                  float* __restrict__ ncnorm,
                                                  float* __restrict__ loss_slot,
                                                  int* __restrict__ counter) {
  __shared__ float T[64][65];
  int tid = threadIdx.x;
  if (blockIdx.x < 2048) {
    int wave = tid >> 6, lane = tid & 63;
    int k = blockIdx.x * 4 + wave;
    float4 v = *(const float4*)(emb + (size_t)k * C_ + lane * 4);
    float ss = v.x*v.x + v.y*v.y + v.z*v.z + v.w*v.w;
    #pragma unroll
    for (int m = 32; m > 0; m >>= 1) ss += __shfl_xor(ss, m);
    if (lane == 0) { cnorm[k] = 0.5f * ss; ncnorm[k] = -0.5f * ss; }
    uint2 p;
    p.x = (unsigned)f2bf_rne(v.x) | ((unsigned)f2bf_rne(v.y) << 16);
    p.y = (unsigned)f2bf_rne(v.z) | ((unsigned)f2bf_rne(v.w) << 16);
    *(uint2*)&Bh[(size_t)k * C_ + lane * 4] = p;
    if (blockIdx.x == 0 && tid == 0) { *loss_slot = 0.0f; *counter = 0; }
  } else {
    int bb = blockIdx.x - 2048;
    int nt = bb >> 2, ct = bb & 3;
    int n0 = nt * 64, c0 = ct * 64;
    int b = n0 >> 10, hw0 = n0 & 1023;
    const float* base = inp + (size_t)b * (C_ * HW_) + hw0;
    #pragma unroll
    for (int i = 0; i < 16; ++i) {
      int cl = i * 4 + (tid >> 6), nl = tid & 63;
      T[nl][cl] = base[(size_t)(c0 + cl) * HW_ + nl];
    }
    __syncthreads();
    #pragma unroll
    for (int i = 0; i < 16; ++i) {
      int nl = i * 4 + (tid >> 6), cl = tid & 63;
      Ah[(size_t)(n0 + nl) * C_ + c0 + cl] = f2bf_rne(T[nl][cl]);
    }
  }
}

// 1-product hh MFMA GEMM; per-(row, 256-sub) top-3 records -> d_out[8MB,16MB), nbe-major.
// Block 128 rows x 1024 codes (4 subs); 4 waves 2x2; swapped operands (codes=M, rows=N).
// v6: COALESCED staging (row-major, within-line XOR permutation) + conflict-free reads.
//     v4's swizzle f(row)=row&3 gave even-qm lanes only 2 chunk-cols -> 4-way conflict
//     (6.29M cyc); v5's chunk-major LDS fixed banks but scattered gld16 sources at
//     512B lane-stride (64 lines/instr vs 16) -> memory-issue bound, 144us.
//     Fix: f(row)=(row>>1)&3. Staging keeps 64B lines intact; fragment rows = 16t+qm
//     so read swizzle = (quad^((qm>>1)&3)) is per-lane constant; per-quad-group
//     chunk-cols perfectly even (8 cols x 2 lanes).
//     Epilogue (v5, kept): acc init = -0.5||e||^2; med3 insert; nbe-major Rec.
__global__ __launch_bounds__(256, 2) void k_gemm1p(const unsigned short* __restrict__ Ah,
                                                   const unsigned short* __restrict__ Bh,
                                                   const float* __restrict__ ncnorm,
                                                   uint4* __restrict__ Rec) {
  // per buffer (bytes): A [0,8192) | B [8192,24576); chunk g at g*16 (A), 8192+g*16 (B)
  __shared__ __align__(16) unsigned short LDS[2][12288];
  __shared__ float mS[2][128][3];

  const int tid = threadIdx.x, lane = tid & 63, wave = tid >> 6;
  const int wr = wave >> 1, wc = wave & 1;
  const int rb = blockIdx.x >> 3, kb = blockIdx.x & 7;
  const int row0 = rb * 128;
  const int qm = lane & 15, quad = lane >> 4;
  const int sw = (quad ^ ((qm >> 1) & 3)) * 8;         // conflict-free XOR swizzle

  // staging: thread g stages row g>>2, stored chunk-slot g&3 holds global chunk (g&3)^f(row)
  const char* srcA[2]; int dstA[2];
  #pragma unroll
  for (int t = 0; t < 2; ++t) {
    int g = t * 256 + tid;
    int row = g >> 2, chs = g & 3, ch = chs ^ ((row >> 1) & 3);
    srcA[t] = (const char*)Ah + (size_t)(row0 + row) * 512 + ch * 16;
    dstA[t] = g * 16;
  }
  const char* srcB[4]; int dstB[4];
  #pragma unroll
  for (int t = 0; t < 4; ++t) {
    int g = t * 256 + tid;
    int r = g >> 2, chs = g & 3, ch = chs ^ ((r >> 1) & 3);
    srcB[t] = (const char*)Bh + (size_t)(kb * 1024 + r) * 512 + ch * 16;
    dstB[t] = 8192 + g * 16;
  }

  // prologue: stage (sub=0, ci=0) into buffer 0
  #pragma unroll
  for (int t = 0; t < 2; ++t) gld16(srcA[t], (char*)LDS[0] + dstA[t]);
  #pragma unroll
  for (int t = 0; t < 4; ++t) gld16(srcB[t], (char*)LDS[0] + dstB[t]);
  __syncthreads();

  const unsigned wq  = (unsigned)(wc * 128 + quad * 4);        // embed bits 7, 3:2
  const unsigned kmk = 0xFFFFFF00u;

  for (int sub = 0; sub < 4; ++sub) {
    const int nbe = kb * 4 + sub;
    // acc init = -cnorm (code = wc*128 + ct*16 + quad*4 + rg; same for all rt)
    const int cb = nbe * 256 + wc * 128 + quad * 4;
    f32x4 acc[4][8];
    {
      float4 ncn[8];
      #pragma unroll
      for (int ct = 0; ct < 8; ++ct) ncn[ct] = *(const float4*)(ncnorm + cb + ct * 16);
      #pragma unroll
      for (int r = 0; r < 4; ++r)
        #pragma unroll
        for (int c = 0; c < 8; ++c) {
          acc[r][c][0] = ncn[c].x; acc[r][c][1] = ncn[c].y;
          acc[r][c][2] = ncn[c].z; acc[r][c][3] = ncn[c].w;
        }
    }

    #pragma unroll 2
    for (int ci = 0; ci < 8; ++ci) {
      const int it = (sub << 3) | ci;
      const int cur = ci & 1;                          // == it&1 (sub*8 even)
      const int nx = it + 1;
      if (nx < 32) {                                   // issue next tile FIRST (overlap)
        const int nsub = nx >> 3, nci = nx & 7, nb = nx & 1;
        #pragma unroll
        for (int t = 0; t < 2; ++t)
          gld16(srcA[t] + nci * 64, (char*)LDS[nb] + dstA[t]);
        #pragma unroll
        for (int t = 0; t < 4; ++t)
          gld16(srcB[t] + nsub * 131072 + nci * 64, (char*)LDS[nb] + dstB[t]);
      }

      const unsigned short* Lb = &LDS[cur][0];
      short8 ah[4];
      #pragma unroll
      for (int rt = 0; rt < 4; ++rt) {
        int row = (wr * 4 + rt) * 16 + qm;             // rows frag: [n=lane&15][k=quad*8+j]
        ah[rt] = *(const short8*)&Lb[row * 32 + sw];
      }
      #pragma unroll
      for (int ch2 = 0; ch2 < 2; ++ch2) {
        short8 bh[4];
        #pragma unroll
        for (int q = 0; q < 4; ++q) {
          int ct = ch2 * 4 + q;
          int r = (wc * 8 + ct) * 16 + qm;             // codes frag: [m=lane&15][k=quad*8+j]
          bh[q] = *(const short8*)&Lb[4096 + r * 32 + sw];
        }
        #pragma unroll
        for (int rt = 0; rt < 4; ++rt)
          #pragma unroll
          for (int q = 0; q < 4; ++q)                  // SWAPPED: codes=A(M), rows=B(N)
            acc[rt][ch2 * 4 + q] =
              __builtin_amdgcn_mfma_f32_16x16x32_bf16(bh[q], ah[rt], acc[rt][ch2 * 4 + q], 0, 0, 0);
      }
      __syncthreads();                                 // drains this iter's stage; 1 barrier/iter
    }

    // epilogue: lane owns row (wr*64+rt*16+qm); acc already = score (cn folded into init).
    // key = score with low 8 mantissa bits = local k; med3 insert (3 ops/elem).
    #pragma unroll
    for (int rt = 0; rt < 4; ++rt) {
      float t1 = -3.4e38f, t2 = t1, t3 = t1;
      #pragma unroll
      for (int ct = 0; ct < 8; ++ct)
        #pragma unroll
        for (int rg = 0; rg < 4; ++rg) {
          unsigned idxv = wq | (unsigned)(ct * 16 + rg);
          float kf = __uint_as_float((__float_as_uint(acc[rt][ct][rg]) & kmk) | idxv);
          float n3 = med3(t2, kf, t3);
          float n2 = med3(t1, kf, t2);
          t1 = fmaxf(t1, kf);
          t2 = n2; t3 = n3;
        }
      #pragma unroll
      for (int m = 16; m < 64; m <<= 1) {              // merge 4 quads (2 steps, 6 ops each)
        float b1 = __shfl_xor(t1, m), b2 = __shfl_xor(t2, m), b3 = __shfl_xor(t3, m);
        float n3 = med3(t2, b1, t3);
        float n2 = med3(t1, b1, t2);
        t1 = fmaxf(t1, b1); t2 = n2; t3 = n3;
        n3 = med3(t2, b2, t3); t2 = fmaxf(t2, b2); t3 = n3;
        t3 = fmaxf(t3, b3);
      }
      if (quad == 0) {
        int rowl = wr * 64 + rt * 16 + qm;
        mS[wc][rowl][0] = t1; mS[wc][rowl][1] = t2; mS[wc][rowl][2] = t3;
      }
    }
    __syncthreads();
    if (tid < 128) {
      float s1 = mS[0][tid][0], s2 = mS[0][tid][1], s3 = mS[0][tid][2];
      float b1 = mS[1][tid][0], b2 = mS[1][tid][1], b3 = mS[1][tid][2];
      float n3 = med3(s2, b1, s3);
      float n2 = med3(s1, b1, s2);
      s1 = fmaxf(s1, b1); s2 = n2; s3 = n3;
      n3 = med3(s2, b2, s3); s2 = fmaxf(s2, b2); s3 = n3;
      s3 = fmaxf(s3, b3);
      unsigned u1 = __float_as_uint(s1), u2 = __float_as_uint(s2), u3 = __float_as_uint(s3);
      uint4 rec;
      rec.x = u1 & kmk;                                // clobbered score (err <= 0.008)
      rec.y = ((unsigned)f2bf_rne(__uint_as_float(u2 & kmk)) << 16)
            |  (unsigned)f2bf_rne(__uint_as_float(u3 & kmk));
      rec.z = (u1 & 255u) | ((u2 & 255u) << 8) | ((u3 & 255u) << 16);
      rec.w = 0u;
      Rec[(size_t)nbe * N_ + row0 + tid] = rec;        // nbe-major: coalesced store
    }
    // no trailing barrier needed: next mS write is >=8 iteration barriers away
  }
}

// per row: global hh-max over 32 subs; count candidates within MARGIN; decide or flag
__global__ __launch_bounds__(64) void k_merge3(const uint4* __restrict__ Rec,
                                               int* __restrict__ fidx,
                                               float* __restrict__ outIdx,
                                               int* __restrict__ list,
                                               int* __restrict__ counter) {
  int row = blockIdx.x * 64 + threadIdx.x;
  float g1 = -3.4e38f; int gk = 0;
  #pragma unroll
  for (int s = 0; s < 32; ++s) {
    uint4 v = Rec[(size_t)s * N_ + row];               // coalesced (nbe-major)
    float s1 = __uint_as_float(v.x);
    if (s1 > g1) { g1 = s1; gk = s * 256 + (int)(v.z & 255u); }
  }
  float thr = g1 - MARGIN;
  int cnt = 0;
  #pragma unroll
  for (int s = 0; s < 32; ++s) {
    uint4 v = Rec[(size_t)s * N_ + row];
    cnt += (__uint_as_float(v.x) >= thr);
    cnt += (bf2f((unsigned short)(v.y >> 16)) >= thr);
    cnt += (bf2f((unsigned short)(v.y & 0xffffu)) >= thr);
  }
  if (cnt == 1) { fidx[row] = gk; outIdx[row] = (float)gk; }
  else { int p = atomicAdd(counter, 1); list[p] = row; }
}

// exact fp32 refine for flagged rows: candidates (<=96) from records, wave-per-candidate dots
__global__ __launch_bounds__(256) void k_refine(const float* __restrict__ inp,
                                                const float* __restrict__ emb,
                                                const float* __restrict__ cnorm,
                                                const uint4* __restrict__ Rec,
                                                const int* __restrict__ list,
                                                const int* __restrict__ counter,
                                                int* __restrict__ fidx,
                                                float* __restrict__ outIdx) {
  __shared__ float f[256];
  __shared__ float ls1[32];
  __shared__ int   ck[96];
  __shared__ float csc[96];
  __shared__ int   ncand;
  int tid = threadIdx.x, lane = tid & 63, wv = tid >> 6;
  int count = *counter;
  for (int i = blockIdx.x; i < count; i += 1024) {
    int row = list[i];
    __syncthreads();
    f[tid] = inp[(size_t)(row >> 10) * (C_ * HW_) + (size_t)tid * HW_ + (row & 1023)];
    if (tid == 0) ncand = 0;
    if (tid < 32) ls1[tid] = __uint_as_float(Rec[(size_t)tid * N_ + row].x);
    __syncthreads();
    float g1 = ls1[0];
    #pragma unroll
    for (int s = 1; s < 32; ++s) g1 = fmaxf(g1, ls1[s]);
    float thr = g1 - MARGIN;
    if (tid < 32) {
      uint4 v = Rec[(size_t)tid * N_ + row];
      float s1 = __uint_as_float(v.x);
      float s2 = bf2f((unsigned short)(v.y >> 16));
      float s3 = bf2f((unsigned short)(v.y & 0xffffu));
      int b = tid * 256;
      if (s1 >= thr) { int p = atomicAdd(&ncand, 1); ck[p] = b + (int)(v.z & 255u); }
      if (s2 >= thr) { int p = atomicAdd(&ncand, 1); ck[p] = b + (int)((v.z >> 8) & 255u); }
      if (s3 >= thr) { int p = atomicAdd(&ncand, 1); ck[p] = b + (int)((v.z >> 16) & 255u); }
    }
    __syncthreads();
    int nc = ncand;
    for (int c = wv; c < nc; c += 4) {
      int k = ck[c];
      float4 e = ((const float4*)(emb + (size_t)k * C_))[lane];
      float d = f[lane*4]*e.x + f[lane*4+1]*e.y + f[lane*4+2]*e.z + f[lane*4+3]*e.w;
      #pragma unroll
      for (int m = 32; m > 0; m >>= 1) d += __shfl_xor(d, m);
      if (lane == 0) csc[c] = d - cnorm[k];
    }
    __syncthreads();
    if (tid == 0) {
      float bs = csc[0]; int bk = ck[0];
      for (int c = 1; c < nc; ++c)
        if (csc[c] > bs || (csc[c] == bs && ck[c] < bk)) { bs = csc[c]; bk = ck[c]; }
      fidx[row] = bk; outIdx[row] = (float)bk;
    }
    __syncthreads();
  }
}

// gather emb[idx] -> NCHW output (overwrites the scratch in d_out) + commitment loss
__global__ __launch_bounds__(256) void k_out(const float* __restrict__ inp,
                                             const float* __restrict__ emb,
                                             const int* __restrict__ fidx,
                                             float* __restrict__ out,
                                             float* __restrict__ loss) {
  __shared__ float Q[32][260];
  int tid = threadIdx.x;
  int n0 = blockIdx.x * 32, b = n0 >> 10, hw0 = n0 & 1023;
  #pragma unroll
  for (int p = 0; p < 8; ++p) {
    int r = p * 4 + (tid >> 6);
    int kq = fidx[n0 + r];
    float4 v = *(const float4*)(emb + (size_t)kq * C_ + (tid & 63) * 4);
    *(float4*)&Q[r][(tid & 63) * 4] = v;
  }
  __syncthreads();
  int hwl = tid & 31, cl = tid >> 5;
  float lsum = 0.0f;
  #pragma unroll
  for (int p = 0; p < 32; ++p) {
    int c = p * 8 + cl;
    size_t a = (size_t)b * (C_ * HW_) + (size_t)c * HW_ + hw0 + hwl;
    float q = Q[hwl][c];
    float x = inp[a];
    out[a] = q;
    float dd = q - x; lsum += dd * dd;
  }
  #pragma unroll
  for (int m = 32; m > 0; m >>= 1) lsum += __shfl_xor(lsum, m);
  __shared__ float red[4];
  if ((tid & 63) == 0) red[tid >> 6] = lsum;
  __syncthreads();
  if (tid == 0)
    atomicAdd(loss, (red[0] + red[1] + red[2] + red[3]) * (0.25f / (float)OUT_SZ));
}

// ---------------- fallback path (round-1 fp32, proven) ----------------
__global__ __launch_bounds__(256) void k_norms_fb(const float* __restrict__ emb,
                                                  float* __restrict__ cnorm,
                                                  float* __restrict__ loss_slot) {
  int tid = threadIdx.x, wave = tid >> 6, lane = tid & 63;
  int k = blockIdx.x * 4 + wave;
  float4 v = *(const float4*)(emb + k * C_ + lane * 4);
  float s = v.x*v.x + v.y*v.y + v.z*v.z + v.w*v.w;
  #pragma unroll
  for (int m = 32; m > 0; m >>= 1) s += __shfl_xor(s, m);
  if (lane == 0) cnorm[k] = 0.5f * s;
  if (blockIdx.x == 0 && tid == 0) *loss_slot = 0.0f;
}

__global__ __launch_bounds__(256) void k_score_fb(const float* __restrict__ inp,
                                                  const float* __restrict__ emb,
                                                  const float* __restrict__ cnorm,
                                                  float* __restrict__ bestS,
                                                  int*   __restrict__ bestK) {
  __shared__ float As[16][132];
  __shared__ float Bs[16][132];
  const int tid = threadIdx.x;
  const int tx = tid & 15, ty = tid >> 4;
  const int rt = blockIdx.x >> 3, ks = blockIdx.x & 7;
  const int row0 = rt * 128;
  const float* Abase = inp + (row0 >> 10) * (C_ * HW_) + (row0 & 1023);
  const int kbase = ks * 1024;
  const int m4  = (tid & 31) << 2;
  const int ccA = tid >> 5;
  const int cc4 = (tid & 3) << 2;
  const int kkB = tid >> 2;

  float rS[8]; int rK[8];
  #pragma unroll
  for (int r = 0; r < 8; ++r) { rS[r] = -3.4e38f; rK[r] = 0; }

  for (int kt = 0; kt < 8; ++kt) {
    const int k0 = kbase + kt * 128;
    float acc[8][8];
    #pragma unroll
    for (int r = 0; r < 8; ++r)
      #pragma unroll
      for (int c = 0; c < 8; ++c) acc[r][c] = 0.f;

    for (int ci = 0; ci < 16; ++ci) {
      const int c0 = ci * 16;
      __syncthreads();
      #pragma unroll
      for (int p = 0; p < 2; ++p) {
        int cc = ccA + p * 8;
        float4 v = *(const float4*)(Abase + (c0 + cc) * HW_ + m4);
        *(float4*)(&As[cc][m4]) = v;
      }
      #pragma unroll
      for (int p = 0; p < 2; ++p) {
        int k = kkB + p * 64;
        float4 v = *(const float4*)(emb + (size_t)(k0 + k) * C_ + c0 + cc4);
        Bs[cc4 + 0][k] = v.x; Bs[cc4 + 1][k] = v.y;
        Bs[cc4 + 2][k] = v.z; Bs[cc4 + 3][k] = v.w;
      }
      __syncthreads();
      #pragma unroll
      for (int cc = 0; cc < 16; ++cc) {
        float4 a0 = *(const float4*)(&As[cc][ty * 8]);
        float4 a1 = *(const float4*)(&As[cc][ty * 8 + 4]);
        float4 b0 = *(const float4*)(&Bs[cc][tx * 8]);
        float4 b1 = *(const float4*)(&Bs[cc][tx * 8 + 4]);
        float a[8] = {a0.x, a0.y, a0.z, a0.w, a1.x, a1.y, a1.z, a1.w};
        float b[8] = {b0.x, b0.y, b0.z, b0.w, b1.x, b1.y, b1.z, b1.w};
        #pragma unroll
        for (int r = 0; r < 8; ++r)
          #pragma unroll
          for (int c = 0; c < 8; ++c) acc[r][c] += a[r] * b[c];
      }
    }
    float cn[8];
    {
      float4 c0v = *(const float4*)(cnorm + k0 + tx * 8);
      float4 c1v = *(const float4*)(cnorm + k0 + tx * 8 + 4);
      cn[0] = c0v.x; cn[1] = c0v.y; cn[2] = c0v.z; cn[3] = c0v.w;
      cn[4] = c1v.x; cn[5] = c1v.y; cn[6] = c1v.z; cn[7] = c1v.w;
    }
    #pragma unroll
    for (int r = 0; r < 8; ++r)
      #pragma unroll
      for (int c = 0; c < 8; ++c) {
        float s = acc[r][c] - cn[c];
        if (s > rS[r]) { rS[r] = s; rK[r] = k0 + tx * 8 + c; }
      }
  }
  #pragma unroll
  for (int r = 0; r < 8; ++r) {
    float s = rS[r]; int kk = rK[r];
    #pragma unroll
    for (int m = 1; m < 16; m <<= 1) {
      float so = __shfl_xor(s, m);
      int   ko = __shfl_xor(kk, m);
      if (so > s || (so == s && ko < kk)) { s = so; kk = ko; }
    }
    if (tx == 0) {
      int row = row0 + ty * 8 + r;
      bestS[ks * N_ + row] = s;
      bestK[ks * N_ + row] = kk;
    }
  }
}

__global__ __launch_bounds__(256) void k_merge_fb(const float* __restrict__ bestS,
                                                  const int*   __restrict__ bestK,
                                                  float* __restrict__ out_idx,
                                                  int*   __restrict__ fidx) {
  int n = blockIdx.x * 256 + threadIdx.x;
  float bs = -3.4e38f; int bk = 0x7fffffff;
  #pragma unroll
  for (int s = 0; s < 8; ++s) {
    float v = bestS[s * N_ + n];
    int  kk = bestK[s * N_ + n];
    if (v > bs || (v == bs && kk < bk)) { bs = v; bk = kk; }
  }
  out_idx[n] = (float)bk;
  fidx[n] = bk;
}

extern "C" void kernel_launch(void* const* d_in, const int* in_sizes, int n_in,
                              void* d_out, int out_size, void* d_ws, size_t ws_size,
                              hipStream_t stream) {
  const float* inp = (const float*)d_in[0];
  const float* emb = (const float*)d_in[1];
  float* out = (float*)d_out;
  char* ws = (char*)d_ws;

  if (ws_size >= (size_t)WS_NEED) {
    unsigned short* Ah = (unsigned short*)d_out;             // [0, 8MB) of d_out
    uint4* Rec = (uint4*)((char*)d_out + 8388608u);          // [8MB, 16MB) of d_out
    unsigned short* Bh = (unsigned short*)(ws + BH_OFF);
    float* cnorm   = (float*)(ws + CNORM_OFF);
    float* ncnorm  = (float*)(ws + NCNORM_OFF);
    int*   list    = (int*)(ws + LIST_OFF);
    int*   counter = (int*)(ws + CNT_OFF);
    int*   fidx    = (int*)(ws + FIDX_OFF);

    conv_fused <<<3072,   256, 0, stream>>>(inp, emb, Ah, Bh, cnorm, ncnorm,
                                            out + LOSS_OFF, counter);
    k_gemm1p   <<<1024,   256, 0, stream>>>(Ah, Bh, ncnorm, Rec);
    k_merge3   <<<N_/64,  64,  0, stream>>>(Rec, fidx, out + IDX_OFF, list, counter);
    k_refine   <<<1024,   256, 0, stream>>>(inp, emb, cnorm, Rec, list, counter,
                                            fidx, out + IDX_OFF);
    k_out      <<<N_/32,  256, 0, stream>>>(inp, emb, fidx, out, out + LOSS_OFF);
  } else {
    float* cnorm = (float*)(ws + FB_CNORM);
    float* bestS = (float*)(ws + FB_BESTS);
    int*   bestK = (int*)(ws + FB_BESTK);
    int*   fidx  = (int*)(ws + FB_FIDX);

    k_norms_fb <<<K_ / 4, 256, 0, stream>>>(emb, cnorm, out + LOSS_OFF);
    k_score_fb <<<1024,   256, 0, stream>>>(inp, emb, cnorm, bestS, bestK);
    k_merge_fb <<<N_/256, 256, 0, stream>>>(bestS, bestK, out + IDX_OFF, fidx);
    k_out      <<<OUT_SZ/8192, 256, 0, stream>>>(inp, emb, fidx, out, out + LOSS_OFF);
  }
}